// Round 1
// baseline (399.418 us; speedup 1.0000x reference)
//
#include <hip/hip_runtime.h>
#include <hip/hip_bf16.h>

#define B_ 2
#define S_ 2048
#define D_ 768
#define H_ 12
#define DH_ 64
#define M_ (B_*S_)     // 4096
#define BH_ (B_*H_)    // 24

typedef __bf16 v8bf __attribute__((ext_vector_type(8)));
typedef __bf16 v4bf __attribute__((ext_vector_type(4)));
typedef float  v4f  __attribute__((ext_vector_type(4)));

static __device__ __forceinline__ v4f mfma16(v8bf a, v8bf b, v4f c) {
  return __builtin_amdgcn_mfma_f32_16x16x32_bf16(a, b, c, 0, 0, 0);
}

// ---------------- fp32 -> bf16 conversion ----------------
__global__ __launch_bounds__(256) void convert_kernel(
    const float* __restrict__ q, const float* __restrict__ k, const float* __restrict__ v,
    const float* __restrict__ Wq, const float* __restrict__ Wk,
    const float* __restrict__ Wv, const float* __restrict__ Wo,
    __bf16* __restrict__ Xq, __bf16* __restrict__ Xk, __bf16* __restrict__ Xv,
    __bf16* __restrict__ Wqb, __bf16* __restrict__ Wkb,
    __bf16* __restrict__ Wvb, __bf16* __restrict__ Wob)
{
  const float* src; __bf16* dst; int n;
  switch (blockIdx.y) {
    case 0: src = q;  dst = Xq;  n = M_*D_; break;
    case 1: src = k;  dst = Xk;  n = M_*D_; break;
    case 2: src = v;  dst = Xv;  n = M_*D_; break;
    case 3: src = Wq; dst = Wqb; n = D_*D_; break;
    case 4: src = Wk; dst = Wkb; n = D_*D_; break;
    case 5: src = Wv; dst = Wvb; n = D_*D_; break;
    default: src = Wo; dst = Wob; n = D_*D_; break;
  }
  int n4 = n >> 2;
  for (int i = blockIdx.x*blockDim.x + threadIdx.x; i < n4; i += gridDim.x*blockDim.x) {
    float4 x = ((const float4*)src)[i];
    v4bf y;
    y[0] = (__bf16)x.x; y[1] = (__bf16)x.y; y[2] = (__bf16)x.z; y[3] = (__bf16)x.w;
    ((v4bf*)dst)[i] = y;
  }
}

// ---------------- shared NT-GEMM core: C[128x128] = A @ W^T ----------------
// A [M x 768] row-major bf16, W [N x 768] row-major bf16 (so K contiguous for both).
// Fragments load directly from global: lane holds 8 contiguous bf16 along K.
static __device__ __forceinline__ void gemm_core(
    const __bf16* __restrict__ A, const __bf16* __restrict__ W,
    int m0, int n0, v4f acc[4][4])
{
  const int lane = threadIdx.x & 63;
  const int wave = threadIdx.x >> 6;
  const int wm = (wave >> 1) << 6;   // wave 64x64 sub-tile
  const int wn = (wave & 1) << 6;
  const int row  = lane & 15;
  const int koff = (lane >> 4) << 3;
  const __bf16* Ab = A + (size_t)(m0 + wm + row) * D_ + koff;
  const __bf16* Wb = W + (size_t)(n0 + wn + row) * D_ + koff;
  for (int k0 = 0; k0 < D_; k0 += 32) {
    v8bf a[4], b[4];
    #pragma unroll
    for (int i = 0; i < 4; i++) a[i] = *(const v8bf*)(Ab + (size_t)(16*i)*D_ + k0);
    #pragma unroll
    for (int j = 0; j < 4; j++) b[j] = *(const v8bf*)(Wb + (size_t)(16*j)*D_ + k0);
    #pragma unroll
    for (int i = 0; i < 4; i++)
      #pragma unroll
      for (int j = 0; j < 4; j++)
        acc[i][j] = mfma16(a[i], b[j], acc[i][j]);
  }
}

// ---------------- QKV projection: write qh/kh [B,H,S,DH], vt [B,H,DH,S] ----------------
__global__ __launch_bounds__(256) void qkv_gemm(
    const __bf16* __restrict__ Xq, const __bf16* __restrict__ Xk, const __bf16* __restrict__ Xv,
    const __bf16* __restrict__ Wqb, const __bf16* __restrict__ Wkb, const __bf16* __restrict__ Wvb,
    const float* __restrict__ bq, const float* __restrict__ bk, const float* __restrict__ bv,
    __bf16* __restrict__ qh, __bf16* __restrict__ kh, __bf16* __restrict__ vt)
{
  const int mode = blockIdx.z;
  const __bf16* A = (mode == 0) ? Xq : (mode == 1) ? Xk : Xv;
  const __bf16* W = (mode == 0) ? Wqb : (mode == 1) ? Wkb : Wvb;
  const float* bias = (mode == 0) ? bq : (mode == 1) ? bk : bv;
  const int m0 = blockIdx.y << 7, n0 = blockIdx.x << 7;
  v4f acc[4][4];
  #pragma unroll
  for (int i = 0; i < 4; i++)
    #pragma unroll
    for (int j = 0; j < 4; j++) { v4f z = {0.f,0.f,0.f,0.f}; acc[i][j] = z; }
  gemm_core(A, W, m0, n0, acc);

  const int lane = threadIdx.x & 63;
  const int wave = threadIdx.x >> 6;
  const int wm = (wave >> 1) << 6, wn = (wave & 1) << 6;
  const int col = lane & 15, quad = lane >> 4;
  float bb[4]; int nn[4];
  #pragma unroll
  for (int j = 0; j < 4; j++) { nn[j] = n0 + wn + 16*j + col; bb[j] = bias[nn[j]]; }

  if (mode < 2) {
    __bf16* dst = (mode == 0) ? qh : kh;
    #pragma unroll
    for (int i = 0; i < 4; i++)
      #pragma unroll
      for (int r = 0; r < 4; r++) {
        int m = m0 + wm + 16*i + quad*4 + r;
        int batch = m >> 11, s = m & (S_-1);
        #pragma unroll
        for (int j = 0; j < 4; j++) {
          int n = nn[j];
          dst[(((size_t)batch*H_ + (n >> 6))*S_ + s)*DH_ + (n & 63)] =
              (__bf16)(acc[i][j][r] + bb[j]);
        }
      }
  } else {
    // V: transposed store -> vt[b][h][d][s], pack 4 consecutive s per lane
    #pragma unroll
    for (int i = 0; i < 4; i++) {
      int mbase = m0 + wm + 16*i + quad*4;
      int batch = mbase >> 11, s0 = mbase & (S_-1);
      #pragma unroll
      for (int j = 0; j < 4; j++) {
        int n = nn[j];
        v4bf pk;
        #pragma unroll
        for (int r = 0; r < 4; r++) pk[r] = (__bf16)(acc[i][j][r] + bb[j]);
        *(v4bf*)(vt + (((size_t)batch*H_ + (n >> 6))*DH_ + (n & 63))*S_ + s0) = pk;
      }
    }
  }
}

// ---------------- flash attention: one wave = 16 queries, 32-key tiles ----------------
__global__ __launch_bounds__(256) void attn_kernel(
    const __bf16* __restrict__ qh, const __bf16* __restrict__ kh, const __bf16* __restrict__ vt,
    const float* __restrict__ mask, __bf16* __restrict__ ao)
{
  __shared__ __bf16 plds[4][2][16][40];   // per-wave, double-buffered, padded (40) rows
  const int bh = blockIdx.y;
  const int wave = threadIdx.x >> 6, lane = threadIdx.x & 63;
  const int col = lane & 15, quad = lane >> 4, koff = quad << 3;
  const int q0 = (blockIdx.x << 6) + (wave << 4);
  const int batch = bh / H_, h = bh % H_;
  const __bf16* qb = qh + (size_t)bh * S_ * DH_;
  const __bf16* kb = kh + (size_t)bh * S_ * DH_;
  const __bf16* vb = vt + (size_t)bh * DH_ * S_;

  v8bf Aq0 = *(const v8bf*)(qb + (size_t)(q0 + col)*DH_ + koff);
  v8bf Aq1 = *(const v8bf*)(qb + (size_t)(q0 + col)*DH_ + 32 + koff);
  v4f O[4];
  #pragma unroll
  for (int f = 0; f < 4; f++) { v4f z = {0.f,0.f,0.f,0.f}; O[f] = z; }
  float mi[4], li[4];
  #pragma unroll
  for (int r = 0; r < 4; r++) { mi[r] = -1e30f; li[r] = 0.f; }
  const float C1 = 0.18033688011112042f;  // log2(e)/sqrt(DH)

  for (int kt = 0; kt < S_; kt += 32) {
    v8bf b00 = *(const v8bf*)(kb + (size_t)(kt + col)*DH_ + koff);
    v8bf b01 = *(const v8bf*)(kb + (size_t)(kt + col)*DH_ + 32 + koff);
    v8bf b10 = *(const v8bf*)(kb + (size_t)(kt + 16 + col)*DH_ + koff);
    v8bf b11 = *(const v8bf*)(kb + (size_t)(kt + 16 + col)*DH_ + 32 + koff);
    v4f s0 = {0.f,0.f,0.f,0.f}, s1 = {0.f,0.f,0.f,0.f};
    s0 = mfma16(Aq0, b00, s0); s0 = mfma16(Aq1, b01, s0);
    s1 = mfma16(Aq0, b10, s1); s1 = mfma16(Aq1, b11, s1);

    __bf16 (*pt)[40] = plds[wave][(kt >> 5) & 1];
    #pragma unroll
    for (int r = 0; r < 4; r++) {
      int srow = q0 + quad*4 + r;
      float x0 = (s0[r] + mask[(size_t)srow*S_ + kt + col]) * C1;
      float x1 = (s1[r] + mask[(size_t)srow*S_ + kt + 16 + col]) * C1;
      float t = fmaxf(x0, x1);
      t = fmaxf(t, __shfl_xor(t, 1));
      t = fmaxf(t, __shfl_xor(t, 2));
      t = fmaxf(t, __shfl_xor(t, 4));
      t = fmaxf(t, __shfl_xor(t, 8));
      float mn = fmaxf(mi[r], t);
      float alpha = exp2f(mi[r] - mn);
      mi[r] = mn;
      float p0 = exp2f(x0 - mn);
      float p1 = exp2f(x1 - mn);
      float rs = p0 + p1;
      rs += __shfl_xor(rs, 1);
      rs += __shfl_xor(rs, 2);
      rs += __shfl_xor(rs, 4);
      rs += __shfl_xor(rs, 8);
      li[r] = li[r]*alpha + rs;
      #pragma unroll
      for (int f = 0; f < 4; f++) O[f][r] *= alpha;
      pt[quad*4 + r][col]      = (__bf16)p0;
      pt[quad*4 + r][16 + col] = (__bf16)p1;
    }
    __syncthreads();  // drains LDS writes (lgkmcnt(0)) before cross-lane read
    v8bf Ap = *(const v8bf*)(&pt[col][koff]);
    #pragma unroll
    for (int f = 0; f < 4; f++) {
      v8bf Bv = *(const v8bf*)(vb + (size_t)(f*16 + col)*S_ + kt + koff);
      O[f] = mfma16(Ap, Bv, O[f]);
    }
  }

  float inv[4];
  #pragma unroll
  for (int r = 0; r < 4; r++) inv[r] = 1.f / li[r];
  #pragma unroll
  for (int f = 0; f < 4; f++)
    #pragma unroll
    for (int r = 0; r < 4; r++) {
      int s = q0 + quad*4 + r;
      ao[((size_t)batch*S_ + s)*D_ + h*DH_ + f*16 + col] = (__bf16)(O[f][r] * inv[r]);
    }
}

// ---------------- output projection: fp32 out ----------------
__global__ __launch_bounds__(256) void out_gemm(
    const __bf16* __restrict__ Ao, const __bf16* __restrict__ Wob,
    const float* __restrict__ bo, float* __restrict__ out)
{
  const int m0 = blockIdx.y << 7, n0 = blockIdx.x << 7;
  v4f acc[4][4];
  #pragma unroll
  for (int i = 0; i < 4; i++)
    #pragma unroll
    for (int j = 0; j < 4; j++) { v4f z = {0.f,0.f,0.f,0.f}; acc[i][j] = z; }
  gemm_core(Ao, Wob, m0, n0, acc);

  const int lane = threadIdx.x & 63;
  const int wave = threadIdx.x >> 6;
  const int wm = (wave >> 1) << 6, wn = (wave & 1) << 6;
  const int col = lane & 15, quad = lane >> 4;
  float bb[4]; int nn[4];
  #pragma unroll
  for (int j = 0; j < 4; j++) { nn[j] = n0 + wn + 16*j + col; bb[j] = bo[nn[j]]; }
  #pragma unroll
  for (int i = 0; i < 4; i++)
    #pragma unroll
    for (int r = 0; r < 4; r++) {
      int m = m0 + wm + 16*i + quad*4 + r;
      #pragma unroll
      for (int j = 0; j < 4; j++)
        out[(size_t)m*D_ + nn[j]] = acc[i][j][r] + bb[j];
    }
}

extern "C" void kernel_launch(void* const* d_in, const int* in_sizes, int n_in,
                              void* d_out, int out_size, void* d_ws, size_t ws_size,
                              hipStream_t stream)
{
  const float* q    = (const float*)d_in[0];
  const float* k    = (const float*)d_in[1];
  const float* v    = (const float*)d_in[2];
  const float* mask = (const float*)d_in[3];
  const float* Wq   = (const float*)d_in[4];
  const float* bq   = (const float*)d_in[5];
  const float* Wk   = (const float*)d_in[6];
  const float* bk   = (const float*)d_in[7];
  const float* Wv   = (const float*)d_in[8];
  const float* bv   = (const float*)d_in[9];
  const float* Wo   = (const float*)d_in[10];
  const float* bo   = (const float*)d_in[11];

  const size_t XN = (size_t)M_ * D_;       // 3145728
  const size_t WN = (size_t)D_ * D_;       // 589824
  const size_t HN = (size_t)BH_ * S_ * DH_;// 3145728

  char* ws = (char*)d_ws;
  __bf16* Xq  = (__bf16*)ws;                 ws += XN * 2;
  __bf16* Xk  = (__bf16*)ws;                 ws += XN * 2;
  __bf16* Xv  = (__bf16*)ws;                 ws += XN * 2;
  __bf16* Wqb = (__bf16*)ws;                 ws += WN * 2;
  __bf16* Wkb = (__bf16*)ws;                 ws += WN * 2;
  __bf16* Wvb = (__bf16*)ws;                 ws += WN * 2;
  __bf16* Wob = (__bf16*)ws;                 ws += WN * 2;
  __bf16* qhb = (__bf16*)ws;                 ws += HN * 2;
  __bf16* khb = (__bf16*)ws;                 ws += HN * 2;
  __bf16* vtb = (__bf16*)ws;                 ws += HN * 2;
  __bf16* aob = (__bf16*)ws;                 ws += XN * 2;  // ~48.8 MB total

  convert_kernel<<<dim3(3072, 7), 256, 0, stream>>>(
      q, k, v, Wq, Wk, Wv, Wo, Xq, Xk, Xv, Wqb, Wkb, Wvb, Wob);
  qkv_gemm<<<dim3(6, 32, 3), 256, 0, stream>>>(
      Xq, Xk, Xv, Wqb, Wkb, Wvb, bq, bk, bv, qhb, khb, vtb);
  attn_kernel<<<dim3(32, 24), 256, 0, stream>>>(qhb, khb, vtb, mask, aob);
  out_gemm<<<dim3(6, 32), 256, 0, stream>>>(aob, Wob, bo, (float*)d_out);
}